// Round 4
// baseline (239.491 us; speedup 1.0000x reference)
//
#include <hip/hip_runtime.h>
#include <cstdint>

#define D 128
#define T 64
#define B 512
#define EPSF 1e-5f

// wave-uniform lane broadcast via v_readlane
__device__ __forceinline__ float lane_bcast(float x, int l) {
    return __int_as_float(__builtin_amdgcn_readlane(__float_as_int(x), l));
}

// swizzled column-pair fetch: logical cpair[j][i2] = (v[i2][j], v[i2+64][j]),
// stored at float2-index j*64 + (i2 ^ ((j&7)<<1)).
//  - uniform-j reads (probe/sweep): lane i2 -> permutation of 0..63 -> conflict-free
//  - per-lane-j float4 reads (judge): float4 idx j*32 + (c ^ (j&7)) -> mod 8 spread
__device__ __forceinline__ float2 colpair(const float* csh, int j, int i2) {
    int f2 = j * 64 + (i2 ^ ((j & 7) << 1));
    return *(const float2*)(csh + 2 * f2);
}

// ---------------------------------------------------------------------------
// prep: writes swizzled column-pair matrix csw (16384 f), vd (128), absb (128)
// ---------------------------------------------------------------------------
__global__ __launch_bounds__(64) void prep_kernel(const float* __restrict__ W,
                                                  const float* __restrict__ b,
                                                  float* __restrict__ csw,
                                                  float* __restrict__ vd,
                                                  float* __restrict__ absb) {
    const int i = blockIdx.x;
    const int l = threadIdx.x;
    float w0 = W[i * D + l];
    float w1 = W[i * D + l + 64];
    float p = w0 * w0 + w1 * w1;
#pragma unroll
    for (int off = 32; off; off >>= 1) p += __shfl_xor(p, off);
    float norm = sqrtf(p);
    float scale = norm > 1e-12f ? norm : 1e-12f;
    float v0 = w0 / scale;   // v[i][l]
    float v1 = w1 / scale;   // v[i][l+64]
    const int i2 = i & 63, half = i >> 6;
    const int sw = (l & 7) << 1;              // ((l+64)&7)<<1 == sw
    csw[2 * (l * 64 + (i2 ^ sw)) + half] = v0;
    csw[2 * ((l + 64) * 64 + (i2 ^ sw)) + half] = v1;
    if (i < 64) { if (l == i) vd[i] = v0; }
    else        { if (l == i - 64) vd[i] = v1; }
    if (i == 0) {
        absb[l] = fabsf(b[l]);
        absb[l + 64] = fabsf(b[l + 64]);
    }
}

// ---------------------------------------------------------------------------
// main RNN kernel. One wave per batch; lane owns rows (lane, lane+64).
// v rows live in REGISTERS (matvec = pure VALU); LDS holds the swizzled
// column-pair copy for probe/sweep/judge column access.
// ---------------------------------------------------------------------------
__global__ __launch_bounds__(128, 1) void rnn_kernel(const float* __restrict__ input,
                                                     const float* __restrict__ target,
                                                     const float* __restrict__ returns,
                                                     const float* __restrict__ W,
                                                     const float* __restrict__ cswg,
                                                     const float* __restrict__ vdg,
                                                     const float* __restrict__ absbg,
                                                     float* __restrict__ out) {
    __shared__ float csh[D * D];       // 64 KB swizzled column pairs
    __shared__ float s_sh[2][2 * 64];  // per-wave interleaved (s_lo, s_hi)
    __shared__ float ae_sh[2 * 64];    // interleaved (aeps_lo, aeps_hi)

    const int tid = threadIdx.x;
    const int w = tid >> 6;
    const int lane = tid & 63;
    const int b = blockIdx.x * 2 + w;
    const int rlo = lane, rhi = lane + 64;

    // cooperative linear copy of csw -> LDS (b128)
    {
        const float4* src = (const float4*)cswg;
        float4* dst = (float4*)csh;
#pragma unroll
        for (int c = 0; c < 32; ++c) dst[c * 128 + tid] = src[c * 128 + tid];
    }

    const float tgt_lo = target[rlo], tgt_hi = target[rhi];
    const float a_lo = absbg[rlo], a_hi = absbg[rhi];
    const float aeps_lo = a_lo + EPSF, aeps_hi = a_hi + EPSF;
    const float vd_lo = vdg[rlo], vd_hi = vdg[rhi];
    const float rvd_lo = 1.0f / vd_lo, rvd_hi = 1.0f / vd_hi;

    if (w == 0) *(float2*)&ae_sh[2 * lane] = make_float2(aeps_lo, aeps_hi);

    // ---- register-resident v rows (lane's two rows), self-normalized ----
    float4 va4[32], vb4[32];
    {
        const float4* wa = (const float4*)(W + rlo * D);
        const float4* wb = (const float4*)(W + rhi * D);
        float na0 = 0, na1 = 0, na2 = 0, na3 = 0;
        float nb0 = 0, nb1 = 0, nb2 = 0, nb3 = 0;
#pragma unroll
        for (int c = 0; c < 32; ++c) {
            float4 A = wa[c], Bv = wb[c];
            va4[c] = A; vb4[c] = Bv;
            na0 = fmaf(A.x, A.x, na0); na1 = fmaf(A.y, A.y, na1);
            na2 = fmaf(A.z, A.z, na2); na3 = fmaf(A.w, A.w, na3);
            nb0 = fmaf(Bv.x, Bv.x, nb0); nb1 = fmaf(Bv.y, Bv.y, nb1);
            nb2 = fmaf(Bv.z, Bv.z, nb2); nb3 = fmaf(Bv.w, Bv.w, nb3);
        }
        float nna = sqrtf((na0 + na1) + (na2 + na3));
        float nnb = sqrtf((nb0 + nb1) + (nb2 + nb3));
        float ra = 1.0f / (nna > 1e-12f ? nna : 1e-12f);
        float rb = 1.0f / (nnb > 1e-12f ? nnb : 1e-12f);
#pragma unroll
        for (int c = 0; c < 32; ++c) {
            va4[c].x *= ra; va4[c].y *= ra; va4[c].z *= ra; va4[c].w *= ra;
            vb4[c].x *= rb; vb4[c].y *= rb; vb4[c].z *= rb; vb4[c].w *= rb;
        }
    }
    __syncthreads();

    const float* va = (const float*)va4;
    const float* vb = (const float*)vb4;

    float h_lo = input[rlo * T * B + b];
    float h_hi = input[rhi * T * B + b];
    out[rlo * T * B + b] = h_lo;
    out[rhi * T * B + b] = h_hi;

    float r_lo = returns[rlo * T * B + b];
    float r_hi = returns[rhi * T * B + b];

    for (int t = 1; t < T; ++t) {
        // ---- adj = h*(1+r)/(1 + sum(h*r)) ----
        float num_lo = h_lo * (1.0f + r_lo);
        float num_hi = h_hi * (1.0f + r_hi);
        float p = h_lo * r_lo + h_hi * r_hi;
#pragma unroll
        for (int off = 32; off; off >>= 1) p += __shfl_xor(p, off);
        float den = 1.0f + p;
        float adj_lo = num_lo / den;
        float adj_hi = num_hi / den;

        if (t < T - 1) {
            r_lo = returns[rlo * T * B + t * B + b];
            r_hi = returns[rhi * T * B + t * B + b];
        }

        const float x_lo = adj_lo - tgt_lo;
        const float x_hi = adj_hi - tgt_hi;

        // ---- s = v @ (adj - pi_bar): pure-VALU register matvec ----
        float a0 = 0, a1 = 0, a2 = 0, a3 = 0;
        float b0 = 0, b1 = 0, b2 = 0, b3 = 0;
#pragma unroll
        for (int k = 0; k < 128; ++k) {
            float xk = (k < 64) ? lane_bcast(x_lo, k) : lane_bcast(x_hi, k - 64);
            switch (k & 3) {
                case 0: a0 = fmaf(va[k], xk, a0); b0 = fmaf(vb[k], xk, b0); break;
                case 1: a1 = fmaf(va[k], xk, a1); b1 = fmaf(vb[k], xk, b1); break;
                case 2: a2 = fmaf(va[k], xk, a2); b2 = fmaf(vb[k], xk, b2); break;
                default: a3 = fmaf(va[k], xk, a3); b3 = fmaf(vb[k], xk, b3); break;
            }
        }
        float s_lo = (a0 + a1) + (a2 + a3);
        float s_hi = (b0 + b1) + (b2 + b3);

        h_lo = adj_lo;
        h_hi = adj_hi;

        bool viol_lo = (s_lo > a_lo) || (s_lo < -a_lo);
        bool viol_hi = (s_hi > a_hi) || (s_hi < -a_hi);
        uint64_t mlo = __ballot(viol_lo);
        uint64_t mhi = __ballot(viol_hi);

        if ((mlo | mhi) != 0ull) {
            // per-lane deltas (reference lam formulas, IEEE div)
            float dl = 0.0f, dh = 0.0f;
            if (s_lo > a_lo) dl = (a_lo - s_lo) / vd_lo;
            else if (s_lo < -a_lo) dl = (-a_lo - s_lo) / vd_lo;
            if (s_hi > a_hi) dh = (a_hi - s_hi) / vd_hi;
            else if (s_hi < -a_hi) dh = (-a_hi - s_hi) / vd_hi;

            int V = __popcll(mlo) + __popcll(mhi);
            bool judge = false;

            if (V <= 8) {
                // q0 shortcut (valid: V<128 so a zero-delta candidate exists)
                bool in_lo = (s_lo < aeps_lo) && (s_lo > -aeps_lo);
                bool in_hi = (s_hi < aeps_hi) && (s_hi > -aeps_hi);
                judge = (__ballot(in_lo && in_hi) == ~0ull);
                if (!judge) {
                    // batch-prefetch all candidate columns, then test
                    uint64_t tml = mlo, tmh = mhi;
                    int jn[8];
                    float djs[8];
                    float2 cps[8];
#pragma unroll
                    for (int q = 0; q < 8; ++q) {
                        int j = -1;
                        if (tml) {
                            j = (int)__ffsll((unsigned long long)tml) - 1;
                            tml &= tml - 1;
                        } else if (tmh) {
                            j = 64 + (int)__ffsll((unsigned long long)tmh) - 1;
                            tmh &= tmh - 1;
                        }
                        jn[q] = j;
                        if (j >= 0) {
                            djs[q] = lane_bcast((j < 64) ? dl : dh, j & 63);
                            cps[q] = colpair(csh, j, lane);
                        }
                    }
#pragma unroll
                    for (int q = 0; q < 8; ++q) {
                        if (jn[q] >= 0 && !judge) {
                            float n_lo = fmaf(cps[q].x, djs[q], s_lo);
                            float n_hi = fmaf(cps[q].y, djs[q], s_hi);
                            bool pl = (n_lo < aeps_lo) && (n_lo > -aeps_lo);
                            bool ph = (n_hi < aeps_hi) && (n_hi > -aeps_hi);
                            if (__ballot(pl && ph) == ~0ull) judge = true;
                        }
                    }
                }
            } else {
                // ---- parallel judge: lane tests candidates j=lane, lane+64 ----
                *(float2*)&s_sh[w][2 * lane] = make_float2(s_lo, s_hi);
                float m1 = -1.0f, m2 = -1.0f;
#pragma unroll
                for (int c = 0; c < 32; ++c) {
                    int f4 = lane * 32 + (c ^ (lane & 7));
                    float4 c1 = *(const float4*)(csh + 4 * f4);
                    float4 c2 = *(const float4*)(csh + 4 * f4 + 8192);
                    float4 sv = *(const float4*)&s_sh[w][4 * c];
                    float4 ae = *(const float4*)&ae_sh[4 * c];
                    m1 = fmaxf(m1, fabsf(fmaf(c1.x, dl, sv.x)) - ae.x);
                    m1 = fmaxf(m1, fabsf(fmaf(c1.y, dl, sv.y)) - ae.y);
                    m1 = fmaxf(m1, fabsf(fmaf(c1.z, dl, sv.z)) - ae.z);
                    m1 = fmaxf(m1, fabsf(fmaf(c1.w, dl, sv.w)) - ae.w);
                    m2 = fmaxf(m2, fabsf(fmaf(c2.x, dh, sv.x)) - ae.x);
                    m2 = fmaxf(m2, fabsf(fmaf(c2.y, dh, sv.y)) - ae.y);
                    m2 = fmaxf(m2, fabsf(fmaf(c2.z, dh, sv.z)) - ae.z);
                    m2 = fmaxf(m2, fabsf(fmaf(c2.w, dh, sv.w)) - ae.w);
                }
                judge = ((__ballot(m1 < 0.0f) | __ballot(m2 < 0.0f)) != 0ull);
            }

            if (judge) {
                // ---- Gauss-Seidel sweep (ascending j, violators only) ----
                uint64_t rem_lo = ~0ull, rem_hi = ~0ull;
                while (true) {
                    uint64_t m1b = __ballot((s_lo > a_lo) || (s_lo < -a_lo)) & rem_lo;
                    uint64_t m2b = __ballot((s_hi > a_hi) || (s_hi < -a_hi)) & rem_hi;
                    int j;
                    if (m1b) {
                        int jl = (int)__ffsll((unsigned long long)m1b) - 1;
                        j = jl;
                        rem_lo = (jl == 63) ? 0ull : (~0ull << (jl + 1));
                    } else if (m2b) {
                        int jh = (int)__ffsll((unsigned long long)m2b) - 1;
                        j = 64 + jh;
                        rem_lo = 0ull;
                        rem_hi = (jh == 63) ? 0ull : (~0ull << (jh + 1));
                    } else {
                        break;
                    }
                    float dl2 = (s_lo > a_lo) ? (a_lo - s_lo) * rvd_lo
                               : ((s_lo < -a_lo) ? (-a_lo - s_lo) * rvd_lo : 0.0f);
                    float dh2 = (s_hi > a_hi) ? (a_hi - s_hi) * rvd_hi
                               : ((s_hi < -a_hi) ? (-a_hi - s_hi) * rvd_hi : 0.0f);
                    float srcv = (j < 64) ? dl2 : dh2;
                    float dj = lane_bcast(srcv, j & 63);
                    if (lane == (j & 63)) {
                        if (j < 64) h_lo += dj; else h_hi += dj;
                    }
                    float2 cp = colpair(csh, j, lane);
                    s_lo = fmaf(cp.x, dj, s_lo);
                    s_hi = fmaf(cp.y, dj, s_hi);
                }
            } else {
                // ---- bisection between pi_bar (s=0) and adj (s), s-space ----
                float hin_lo = tgt_lo, hin_hi = tgt_hi;
                float sin_lo = 0.0f, sin_hi = 0.0f;
                float hout_lo = h_lo, hout_hi = h_hi;
                float sout_lo = s_lo, sout_hi = s_hi;
                float hm_lo = 0.0f, hm_hi = 0.0f;
#pragma unroll
                for (int it = 0; it < 10; ++it) {
                    hm_lo = hin_lo + (hout_lo - hin_lo) * 0.5f;
                    hm_hi = hin_hi + (hout_hi - hin_hi) * 0.5f;
                    float sm_lo = sin_lo + (sout_lo - sin_lo) * 0.5f;
                    float sm_hi = sin_hi + (sout_hi - sin_hi) * 0.5f;
                    bool pl = (sm_lo <= aeps_lo) && (sm_lo >= -aeps_lo);
                    bool ph = (sm_hi <= aeps_hi) && (sm_hi >= -aeps_hi);
                    bool inside = (__ballot(pl && ph) == ~0ull);
                    if (inside) {
                        hin_lo = hm_lo; hin_hi = hm_hi;
                        sin_lo = sm_lo; sin_hi = sm_hi;
                    } else {
                        hout_lo = hm_lo; hout_hi = hm_hi;
                        sout_lo = sm_lo; sout_hi = sm_hi;
                    }
                }
                h_lo = hm_lo;
                h_hi = hm_hi;
            }
        }
        // else: no violators -> judge=1, sweep no-op, h = adj unchanged

        out[rlo * T * B + t * B + b] = h_lo;
        out[rhi * T * B + t * B + b] = h_hi;
    }

    out[D * T * B + rlo * B + b] = h_lo;
    out[D * T * B + rhi * B + b] = h_hi;
}

extern "C" void kernel_launch(void* const* d_in, const int* in_sizes, int n_in,
                              void* d_out, int out_size, void* d_ws, size_t ws_size,
                              hipStream_t stream) {
    const float* input   = (const float*)d_in[0];
    const float* target  = (const float*)d_in[1];
    const float* returns = (const float*)d_in[2];
    // d_in[3] = hidden (unused by the reference)
    const float* W = (const float*)d_in[4];
    const float* b = (const float*)d_in[5];
    float* out = (float*)d_out;

    float* csw  = (float*)d_ws;            // 16384 floats (swizzled col-pairs)
    float* vd   = csw + D * D;             // 128 floats
    float* absb = vd + D;                  // 128 floats

    prep_kernel<<<D, 64, 0, stream>>>(W, b, csw, vd, absb);
    rnn_kernel<<<B / 2, 128, 0, stream>>>(input, target, returns, W, csw, vd, absb, out);
}

// Round 5
// 235.489 us; speedup vs baseline: 1.0170x; 1.0170x over previous
//
#include <hip/hip_runtime.h>
#include <cstdint>

#define D 128
#define T 64
#define B 512
#define EPSF 1e-5f

// wave-uniform lane broadcast via v_readlane
__device__ __forceinline__ float lane_bcast(float x, int l) {
    return __int_as_float(__builtin_amdgcn_readlane(__float_as_int(x), l));
}

// swizzled column-pair fetch: logical cpair[j][i2] = (v[i2][j], v[i2+64][j]),
// stored at float2-index j*64 + (i2 ^ ((j&7)<<1)).
// uniform-j reads: lane i2 -> permutation of 0..63 -> conflict-free.
__device__ __forceinline__ float2 colpair(const float* csh, int j, int i2) {
    int f2 = j * 64 + (i2 ^ ((j & 7) << 1));
    return *(const float2*)(csh + 2 * f2);
}

// ---------------------------------------------------------------------------
// prep: writes swizzled column-pair matrix csw (16384 f), vd (128), absb (128)
// ---------------------------------------------------------------------------
__global__ __launch_bounds__(64) void prep_kernel(const float* __restrict__ W,
                                                  const float* __restrict__ b,
                                                  float* __restrict__ csw,
                                                  float* __restrict__ vd,
                                                  float* __restrict__ absb) {
    const int i = blockIdx.x;
    const int l = threadIdx.x;
    float w0 = W[i * D + l];
    float w1 = W[i * D + l + 64];
    float p = w0 * w0 + w1 * w1;
#pragma unroll
    for (int off = 32; off; off >>= 1) p += __shfl_xor(p, off);
    float norm = sqrtf(p);
    float scale = norm > 1e-12f ? norm : 1e-12f;
    float v0 = w0 / scale;   // v[i][l]
    float v1 = w1 / scale;   // v[i][l+64]
    const int i2 = i & 63, half = i >> 6;
    const int sw = (l & 7) << 1;              // ((l+64)&7)<<1 == sw
    csw[2 * (l * 64 + (i2 ^ sw)) + half] = v0;
    csw[2 * ((l + 64) * 64 + (i2 ^ sw)) + half] = v1;
    if (i < 64) { if (l == i) vd[i] = v0; }
    else        { if (l == i - 64) vd[i] = v1; }
    if (i == 0) {
        absb[l] = fabsf(b[l]);
        absb[l + 64] = fabsf(b[l + 64]);
    }
}

// ---------------------------------------------------------------------------
// main RNN kernel. One wave per batch; lane owns rows (lane, lane+64).
// Single column-pair LDS layout serves matvec, probe, sweep, and judge.
// ---------------------------------------------------------------------------
__global__ __launch_bounds__(128) void rnn_kernel(const float* __restrict__ input,
                                                  const float* __restrict__ target,
                                                  const float* __restrict__ returns,
                                                  const float* __restrict__ cswg,
                                                  const float* __restrict__ vdg,
                                                  const float* __restrict__ absbg,
                                                  float* __restrict__ out) {
    __shared__ float csh[D * D];       // 64 KB swizzled column pairs
    __shared__ float s_sh[2][2 * 64];  // per-wave interleaved (s_lo, s_hi)
    __shared__ float ae_sh[2 * 64];    // interleaved (aeps_lo, aeps_hi)

    const int tid = threadIdx.x;
    const int w = tid >> 6;
    const int lane = tid & 63;
    const int b = blockIdx.x * 2 + w;
    const int rlo = lane, rhi = lane + 64;

    // cooperative linear copy of csw -> LDS (b128)
    {
        const float4* src = (const float4*)cswg;
        float4* dst = (float4*)csh;
#pragma unroll
        for (int c = 0; c < 32; ++c) dst[c * 128 + tid] = src[c * 128 + tid];
    }

    const float tgt_lo = target[rlo], tgt_hi = target[rhi];
    const float a_lo = absbg[rlo], a_hi = absbg[rhi];
    const float aeps_lo = a_lo + EPSF, aeps_hi = a_hi + EPSF;
    const float vd_lo = vdg[rlo], vd_hi = vdg[rhi];
    const float rvd_lo = 1.0f / vd_lo, rvd_hi = 1.0f / vd_hi;

    if (w == 0) *(float2*)&ae_sh[2 * lane] = make_float2(aeps_lo, aeps_hi);
    __syncthreads();

    // matvec column base pointers: column k at colp[k&7] + k*512 bytes
    const char* colp[8];
#pragma unroll
    for (int c = 0; c < 8; ++c)
        colp[c] = (const char*)csh + 8 * (lane ^ (c << 1));

    float h_lo = input[rlo * T * B + b];
    float h_hi = input[rhi * T * B + b];
    out[rlo * T * B + b] = h_lo;
    out[rhi * T * B + b] = h_hi;

    float r_lo = returns[rlo * T * B + b];
    float r_hi = returns[rhi * T * B + b];

    for (int t = 1; t < T; ++t) {
        // ---- adj = h*(1+r)/(1 + sum(h*r)) ----
        float num_lo = h_lo * (1.0f + r_lo);
        float num_hi = h_hi * (1.0f + r_hi);
        float p = h_lo * r_lo + h_hi * r_hi;
#pragma unroll
        for (int off = 32; off; off >>= 1) p += __shfl_xor(p, off);
        float den = 1.0f + p;
        float adj_lo = num_lo / den;
        float adj_hi = num_hi / den;

        if (t < T - 1) {
            r_lo = returns[rlo * T * B + t * B + b];
            r_hi = returns[rhi * T * B + t * B + b];
        }

        const float x_lo = adj_lo - tgt_lo;
        const float x_hi = adj_hi - tgt_hi;

        // ---- s = v @ (adj - pi_bar): ds_read_b64 per k, imm offsets ----
        float a0 = 0, a1 = 0, a2 = 0, a3 = 0;
        float b0 = 0, b1 = 0, b2 = 0, b3 = 0;
#pragma unroll
        for (int k = 0; k < 128; ++k) {
            float2 cp = *(const float2*)(colp[k & 7] + k * 512);
            float xk = lane_bcast((k < 64) ? x_lo : x_hi, k & 63);
            switch (k & 3) {
                case 0: a0 = fmaf(cp.x, xk, a0); b0 = fmaf(cp.y, xk, b0); break;
                case 1: a1 = fmaf(cp.x, xk, a1); b1 = fmaf(cp.y, xk, b1); break;
                case 2: a2 = fmaf(cp.x, xk, a2); b2 = fmaf(cp.y, xk, b2); break;
                default: a3 = fmaf(cp.x, xk, a3); b3 = fmaf(cp.y, xk, b3); break;
            }
        }
        float s_lo = (a0 + a1) + (a2 + a3);
        float s_hi = (b0 + b1) + (b2 + b3);

        h_lo = adj_lo;
        h_hi = adj_hi;

        uint64_t mlo = __ballot(fabsf(s_lo) > a_lo);
        uint64_t mhi = __ballot(fabsf(s_hi) > a_hi);

        if ((mlo | mhi) != 0ull) {
            // per-lane candidate deltas from ORIGINAL s (reference semantics)
            float dl = 0.0f, dh = 0.0f;
            if (s_lo > a_lo) dl = (a_lo - s_lo) / vd_lo;
            else if (s_lo < -a_lo) dl = (-a_lo - s_lo) / vd_lo;
            if (s_hi > a_hi) dh = (a_hi - s_hi) / vd_hi;
            else if (s_hi < -a_hi) dh = (-a_hi - s_hi) / vd_hi;

            int V = __popcll(mlo) + __popcll(mhi);
            bool judge = false;

            if (V <= 8) {
                // q0: V<128 so a zero-delta candidate exists
                bool in_lo = (s_lo < aeps_lo) && (s_lo > -aeps_lo);
                bool in_hi = (s_hi < aeps_hi) && (s_hi > -aeps_hi);
                judge = (__ballot(in_lo && in_hi) == ~0ull);
                if (!judge) {
                    // batch-prefetch all candidate columns, then test
                    uint64_t tml = mlo, tmh = mhi;
                    int jn[8];
                    float djs[8];
                    float2 cps[8];
#pragma unroll
                    for (int q = 0; q < 8; ++q) {
                        int j = -1;
                        if (tml) {
                            j = (int)__ffsll((unsigned long long)tml) - 1;
                            tml &= tml - 1;
                        } else if (tmh) {
                            j = 64 + (int)__ffsll((unsigned long long)tmh) - 1;
                            tmh &= tmh - 1;
                        }
                        jn[q] = j;
                        if (j >= 0) {
                            djs[q] = lane_bcast((j < 64) ? dl : dh, j & 63);
                            cps[q] = colpair(csh, j, lane);
                        }
                    }
#pragma unroll
                    for (int q = 0; q < 8; ++q) {
                        if (jn[q] >= 0 && !judge) {
                            float n_lo = fmaf(cps[q].x, djs[q], s_lo);
                            float n_hi = fmaf(cps[q].y, djs[q], s_hi);
                            bool pl = (n_lo < aeps_lo) && (n_lo > -aeps_lo);
                            bool ph = (n_hi < aeps_hi) && (n_hi > -aeps_hi);
                            if (__ballot(pl && ph) == ~0ull) judge = true;
                        }
                    }
                }
            } else {
                // ---- parallel judge: lane tests candidates j=lane, lane+64 ----
                *(float2*)&s_sh[w][2 * lane] = make_float2(s_lo, s_hi);
                float m1 = -1.0f, m2 = -1.0f;
#pragma unroll
                for (int c = 0; c < 32; ++c) {
                    int f4 = lane * 32 + (c ^ (lane & 7));
                    float4 c1 = *(const float4*)(csh + 4 * f4);
                    float4 c2 = *(const float4*)(csh + 4 * f4 + 8192);
                    int i2a = (2 * c) ^ ((lane & 7) << 1);
                    float4 sv = *(const float4*)&s_sh[w][2 * i2a];
                    float4 ae = *(const float4*)&ae_sh[2 * i2a];
                    m1 = fmaxf(m1, fabsf(fmaf(c1.x, dl, sv.x)) - ae.x);
                    m1 = fmaxf(m1, fabsf(fmaf(c1.y, dl, sv.y)) - ae.y);
                    m1 = fmaxf(m1, fabsf(fmaf(c1.z, dl, sv.z)) - ae.z);
                    m1 = fmaxf(m1, fabsf(fmaf(c1.w, dl, sv.w)) - ae.w);
                    m2 = fmaxf(m2, fabsf(fmaf(c2.x, dh, sv.x)) - ae.x);
                    m2 = fmaxf(m2, fabsf(fmaf(c2.y, dh, sv.y)) - ae.y);
                    m2 = fmaxf(m2, fabsf(fmaf(c2.z, dh, sv.z)) - ae.z);
                    m2 = fmaxf(m2, fabsf(fmaf(c2.w, dh, sv.w)) - ae.w);
                }
                judge = ((__ballot(m1 < 0.0f) | __ballot(m2 < 0.0f)) != 0ull);
            }

            if (judge) {
                // ---- speculative batched Gauss-Seidel sweep (ascending j) ----
                uint64_t rem_lo = ~0ull, rem_hi = ~0ull;
                while (true) {
                    uint64_t vl = __ballot(fabsf(s_lo) > a_lo) & rem_lo;
                    uint64_t vh = __ballot(fabsf(s_hi) > a_hi) & rem_hi;
                    if (!(vl | vh)) break;
                    // select up to 4 ascending candidates; prefetch columns
                    int jq[4];
                    float2 cpq[4];
                    {
                        uint64_t tl = vl, th = vh;
#pragma unroll
                        for (int q = 0; q < 4; ++q) {
                            int j = -1;
                            if (tl) {
                                j = (int)__ffsll((unsigned long long)tl) - 1;
                                tl &= tl - 1;
                            } else if (th) {
                                j = 64 + (int)__ffsll((unsigned long long)th) - 1;
                                th &= th - 1;
                            }
                            jq[q] = j;
                            if (j >= 0) cpq[q] = colpair(csh, j, lane);
                        }
                    }
                    bool abort = false;
#pragma unroll
                    for (int q = 0; q < 4; ++q) {
                        if (abort || jq[q] < 0) continue;
                        // current lowest violator in the remaining window
                        uint64_t cl = __ballot(fabsf(s_lo) > a_lo) & rem_lo;
                        uint64_t ch = __ballot(fabsf(s_hi) > a_hi) & rem_hi;
                        int jl = cl ? (int)__ffsll((unsigned long long)cl) - 1
                                    : (ch ? 64 + (int)__ffsll((unsigned long long)ch) - 1 : -1);
                        if (jl < 0) { rem_lo = rem_hi = 0ull; abort = true; continue; }
                        if (jl < jq[q]) { abort = true; continue; }  // new violator: refetch
                        if (jl > jq[q]) continue;                    // candidate fixed: skip
                        // jl == jq[q]: apply (delta from CURRENT s)
                        float tl2 = (s_lo > a_lo) ? (a_lo - s_lo)
                                   : ((s_lo < -a_lo) ? (-a_lo - s_lo) : 0.0f);
                        float th2 = (s_hi > a_hi) ? (a_hi - s_hi)
                                   : ((s_hi < -a_hi) ? (-a_hi - s_hi) : 0.0f);
                        float dj = lane_bcast((jq[q] < 64) ? tl2 * rvd_lo : th2 * rvd_hi,
                                              jq[q] & 63);
                        if (lane == (jq[q] & 63)) {
                            if (jq[q] < 64) h_lo += dj; else h_hi += dj;
                        }
                        s_lo = fmaf(cpq[q].x, dj, s_lo);
                        s_hi = fmaf(cpq[q].y, dj, s_hi);
                        if (jq[q] < 64) {
                            rem_lo = (jq[q] == 63) ? 0ull : (~0ull << (jq[q] + 1));
                        } else {
                            rem_lo = 0ull;
                            int sh = jq[q] - 64;
                            rem_hi = (sh == 63) ? 0ull : (~0ull << (sh + 1));
                        }
                    }
                    if (!(rem_lo | rem_hi)) break;
                }
            } else {
                // ---- bisection between pi_bar (s=0) and adj (s), s-space ----
                float hin_lo = tgt_lo, hin_hi = tgt_hi;
                float sin_lo = 0.0f, sin_hi = 0.0f;
                float hout_lo = h_lo, hout_hi = h_hi;
                float sout_lo = s_lo, sout_hi = s_hi;
                float hm_lo = 0.0f, hm_hi = 0.0f;
#pragma unroll
                for (int it = 0; it < 10; ++it) {
                    hm_lo = hin_lo + (hout_lo - hin_lo) * 0.5f;
                    hm_hi = hin_hi + (hout_hi - hin_hi) * 0.5f;
                    float sm_lo = sin_lo + (sout_lo - sin_lo) * 0.5f;
                    float sm_hi = sin_hi + (sout_hi - sin_hi) * 0.5f;
                    bool pl = (sm_lo <= aeps_lo) && (sm_lo >= -aeps_lo);
                    bool ph = (sm_hi <= aeps_hi) && (sm_hi >= -aeps_hi);
                    bool inside = (__ballot(pl && ph) == ~0ull);
                    if (inside) {
                        hin_lo = hm_lo; hin_hi = hm_hi;
                        sin_lo = sm_lo; sin_hi = sm_hi;
                    } else {
                        hout_lo = hm_lo; hout_hi = hm_hi;
                        sout_lo = sm_lo; sout_hi = sm_hi;
                    }
                }
                h_lo = hm_lo;
                h_hi = hm_hi;
            }
        }
        // else: no violators -> judge=1, sweep no-op, h = adj unchanged

        out[rlo * T * B + t * B + b] = h_lo;
        out[rhi * T * B + t * B + b] = h_hi;
    }

    out[D * T * B + rlo * B + b] = h_lo;
    out[D * T * B + rhi * B + b] = h_hi;
}

extern "C" void kernel_launch(void* const* d_in, const int* in_sizes, int n_in,
                              void* d_out, int out_size, void* d_ws, size_t ws_size,
                              hipStream_t stream) {
    const float* input   = (const float*)d_in[0];
    const float* target  = (const float*)d_in[1];
    const float* returns = (const float*)d_in[2];
    // d_in[3] = hidden (unused by the reference)
    const float* W = (const float*)d_in[4];
    const float* b = (const float*)d_in[5];
    float* out = (float*)d_out;

    float* csw  = (float*)d_ws;            // 16384 floats (swizzled col-pairs)
    float* vd   = csw + D * D;             // 128 floats
    float* absb = vd + D;                  // 128 floats

    prep_kernel<<<D, 64, 0, stream>>>(W, b, csw, vd, absb);
    rnn_kernel<<<B / 2, 128, 0, stream>>>(input, target, returns, csw, vd, absb, out);
}